// Round 1
// baseline (499.646 us; speedup 1.0000x reference)
//
#include <hip/hip_runtime.h>
#include <hip/hip_bf16.h>
#include <math.h>

// Problem constants (from reference setup_inputs)
#define BN  8
#define QN  2048
#define KN  2048
#define FN  512
#define FVN 512

typedef __bf16 bf16x8 __attribute__((ext_vector_type(8)));
typedef __bf16 bf16x4v __attribute__((ext_vector_type(4)));
typedef float  f32x4  __attribute__((ext_vector_type(4)));

__device__ inline bf16x8 pack8(float4 a, float4 b) {
  bf16x8 r;
  r[0] = (__bf16)a.x; r[1] = (__bf16)a.y; r[2] = (__bf16)a.z; r[3] = (__bf16)a.w;
  r[4] = (__bf16)b.x; r[5] = (__bf16)b.y; r[6] = (__bf16)b.z; r[7] = (__bf16)b.w;
  return r;
}

// Async global->LDS, 16B/lane. LDS dest = wave-uniform base + lane*16 (m97).
__device__ __forceinline__ void g2l16(const __bf16* g, __bf16* l) {
  __builtin_amdgcn_global_load_lds(
      (const __attribute__((address_space(1))) void*)g,
      (__attribute__((address_space(3))) void*)l,
      16, 0, 0);
}

// ---------------------------------------------------------------------------
// Kernel 0 (prep): y==0 -> q convert (pre-scaled), y==1 -> k convert,
//                  y==2 -> v transpose to Vt[b, fv, k] bf16, y==3 -> zero sums.
// ---------------------------------------------------------------------------
__global__ __launch_bounds__(256) void prep(
    const float* __restrict__ qm, const float* __restrict__ km,
    const float* __restrict__ vm,
    __bf16* __restrict__ qb, __bf16* __restrict__ kb, __bf16* __restrict__ Vt,
    float* __restrict__ sums) {
  const int tid = threadIdx.x;
  if (blockIdx.y == 0) {
    const size_t idx = ((size_t)blockIdx.x * 256 + tid) * 8;
    const float scale = 0.044194173824159216f;  // 512^-0.5
    float4 a = *(const float4*)(qm + idx);
    float4 b = *(const float4*)(qm + idx + 4);
    a.x *= scale; a.y *= scale; a.z *= scale; a.w *= scale;
    b.x *= scale; b.y *= scale; b.z *= scale; b.w *= scale;
    *(bf16x8*)(qb + idx) = pack8(a, b);
  } else if (blockIdx.y == 1) {
    const size_t idx = ((size_t)blockIdx.x * 256 + tid) * 8;
    float4 a = *(const float4*)(km + idx);
    float4 b = *(const float4*)(km + idx + 4);
    *(bf16x8*)(kb + idx) = pack8(a, b);
  } else if (blockIdx.y == 2) {
    // v transpose: 2048 logical blocks; bx = ((b*8)+fblk)*32 + kblk
    const int bx = blockIdx.x;
    if (bx >= (KN / 64) * (FVN / 64) * BN) return;
    const int b  = bx >> 8;                 // /(32*8)
    const int f0 = ((bx >> 5) & 7) * 64;
    const int k0 = (bx & 31) * 64;
    __shared__ float tile[64][65];
    const int r = tid >> 4;          // 0..15
    const int c = (tid & 15) * 4;    // 0..60
#pragma unroll
    for (int i = 0; i < 4; i++) {
      float4 u = *(const float4*)(vm + ((size_t)b * KN + k0 + r + i * 16) * FVN + f0 + c);
      tile[r + i * 16][c] = u.x; tile[r + i * 16][c + 1] = u.y;
      tile[r + i * 16][c + 2] = u.z; tile[r + i * 16][c + 3] = u.w;
    }
    __syncthreads();
#pragma unroll
    for (int i = 0; i < 4; i++) {
      int fv = r + i * 16;
      bf16x4v w;
      w[0] = (__bf16)tile[c][fv];     w[1] = (__bf16)tile[c + 1][fv];
      w[2] = (__bf16)tile[c + 2][fv]; w[3] = (__bf16)tile[c + 3][fv];
      *(bf16x4v*)(Vt + ((size_t)b * FVN + f0 + fv) * KN + k0 + c) = w;
    }
  } else {
    // zero sums[BN*QN] f32 = 64 KB: 16 blocks x 256 thr x 16B
    if (blockIdx.x < (BN * QN) / 1024) {
      float4 z4; z4.x = 0.f; z4.y = 0.f; z4.z = 0.f; z4.w = 0.f;
      ((float4*)sums)[(size_t)blockIdx.x * 256 + tid] = z4;
    }
  }
}

// ---------------------------------------------------------------------------
// Kernel 1: S[z,q,k] = (bf16) dot(qb[b,q,:], kb[b,k,:])   (scale pre-folded)
// 128x128 tile, BK=64 as two m97-verified [128][32] LDS half-tiles.
// Epilogue additionally accumulates row-sums of exp(S) into sums[b,q]
// (16-lane shfl reduce -> 1 atomicAdd per row per wave-half).
// ---------------------------------------------------------------------------
__global__ __launch_bounds__(256) void gemm_s(
    const __bf16* __restrict__ qb, const __bf16* __restrict__ kb,
    __bf16* __restrict__ Sws, float* __restrict__ sums,
    int b0, int q0, int qchunk) {
  __shared__ __align__(16) __bf16 As[2][128][32];  // 16 KB, k-half h
  __shared__ __align__(16) __bf16 Bs[2][128][32];
  const int tid = threadIdx.x;
  const int lane = tid & 63, wave = tid >> 6;
  const int wq = (wave & 1) * 64, wk = (wave >> 1) * 64;
  const int qt = blockIdx.x * 128, kt = blockIdx.y * 128;
  const int z = blockIdx.z, b = b0 + z;
  __bf16* S = Sws + (size_t)z * qchunk * KN;
  const __bf16* Ab = qb + ((size_t)b * QN + q0 + qt) * FN;
  const __bf16* Bb = kb + ((size_t)b * KN + kt) * FN;
  const int srow = lane >> 2;         // 0..15 within 16-row group
  const int scol = (lane & 3) * 8;    // bf16 col within 32
  const int r = lane & 15, quad = lane >> 4;
  f32x4 acc[4][4] = {};
  for (int f0 = 0; f0 < FN; f0 += 64) {
    __syncthreads();                  // prev-iter frag reads done
#pragma unroll
    for (int h = 0; h < 2; h++) {
      const int co = f0 + h * 32 + scol;
      g2l16(Ab + (size_t)(wave * 32 + srow) * FN + co,      &As[h][wave * 32][0]);
      g2l16(Ab + (size_t)(wave * 32 + 16 + srow) * FN + co, &As[h][wave * 32 + 16][0]);
      g2l16(Bb + (size_t)(wave * 32 + srow) * FN + co,      &Bs[h][wave * 32][0]);
      g2l16(Bb + (size_t)(wave * 32 + 16 + srow) * FN + co, &Bs[h][wave * 32 + 16][0]);
    }
    __syncthreads();                  // vmcnt drain + visibility
#pragma unroll
    for (int h = 0; h < 2; h++) {
      bf16x8 af[4], bf[4];
#pragma unroll
      for (int i = 0; i < 4; i++) af[i] = *(bf16x8*)&As[h][wq + i * 16 + r][quad * 8];
#pragma unroll
      for (int j = 0; j < 4; j++) bf[j] = *(bf16x8*)&Bs[h][wk + j * 16 + r][quad * 8];
#pragma unroll
      for (int i = 0; i < 4; i++)
#pragma unroll
        for (int j = 0; j < 4; j++)
          acc[i][j] = __builtin_amdgcn_mfma_f32_16x16x32_bf16(af[i], bf[j], acc[i][j], 0, 0, 0);
    }
  }
  // C/D layout (m89-verified): col = lane&15 (=k), row = quad*4+reg (=q)
#pragma unroll
  for (int i = 0; i < 4; i++)
#pragma unroll
    for (int j = 0; j < 4; j++)
#pragma unroll
      for (int t = 0; t < 4; t++) {
        int qq = qt + wq + i * 16 + quad * 4 + t;
        int kk = kt + wk + j * 16 + r;
        S[(size_t)qq * KN + kk] = (__bf16)acc[i][j][t];
      }
  // Row-sum of exp over this block's 64 k-cols per wave (denominator is
  // UNMASKED sum over all k; partials from the 16 kt-blocks accumulate).
#pragma unroll
  for (int i = 0; i < 4; i++)
#pragma unroll
    for (int t = 0; t < 4; t++) {
      float part = 0.f;
#pragma unroll
      for (int j = 0; j < 4; j++) part += __expf(acc[i][j][t]);
      part += __shfl_xor(part, 1);
      part += __shfl_xor(part, 2);
      part += __shfl_xor(part, 4);
      part += __shfl_xor(part, 8);
      if (r == 0)
        atomicAdd(&sums[(size_t)b * QN + q0 + qt + wq + i * 16 + quad * 4 + t], part);
    }
}

// ---------------------------------------------------------------------------
// Kernel 2 (fused softmax+bias+mask+PV): out[b,q,fv] = sum_k W[q,k]*Vt[fv,k]
// with W computed on the fly in the A-staging path:
//   W = attn ? 0 : (exp(S)/sum - (alibi ? 0 : dist(q,k)*bias_scale))
// Tile: 64q x 512fv (full FV -> masks read exactly once), 8 waves (512 thr).
// b = blockIdx.x % nb -> batch<->XCD affinity keeps Vt (2MB/batch) L2-hot.
// A-chunk (S/masks/coords) prefetched one k-step ahead (issue-early, T14).
// ---------------------------------------------------------------------------
__global__ __launch_bounds__(512) void gemm_wv(
    const __bf16* __restrict__ Sws, const __bf16* __restrict__ Vt,
    const float* __restrict__ sums,
    const float* __restrict__ cq, const float* __restrict__ ck,
    const int* __restrict__ attn, const int* __restrict__ alibi,
    const float* __restrict__ bsp, float* __restrict__ out,
    int b0, int q0, int qchunk, int nb) {
  __shared__ __align__(16) __bf16 As[2][64][32];    // [h][q][k-half]  8 KB
  __shared__ __align__(16) __bf16 Bs[2][512][32];   // [h][fv][k-half] 64 KB
  const int tid = threadIdx.x;
  const int lane = tid & 63, wave = tid >> 6;
  const int flat = blockIdx.x;
  const int z = flat & (nb - 1);            // nb is a power of two
  const int b = b0 + z;
  const int qt = (flat / nb) * 64;
  // --- A-staging thread mapping: 512 thr = 64 rows x 8 k-chunks-of-8 ---
  const int arow_i = tid >> 3;              // 0..63 local q row
  const int ac8 = tid & 7;                  // 0..7  k chunk
  const int qg = q0 + qt + arow_i;
  const __bf16* Srow = Sws + ((size_t)z * qchunk + qt + arow_i) * KN;
  const int* arow = attn + ((size_t)b * QN + qg) * KN;
  const int* lrow = alibi + ((size_t)b * QN + qg) * KN;
  const float* ckb = ck + (size_t)b * KN * 2;
  const float inv = 1.0f / sums[(size_t)b * QN + qg];
  const float qx = cq[((size_t)b * QN + qg) * 2 + 0];
  const float qy = cq[((size_t)b * QN + qg) * 2 + 1];
  const float bs = bsp[0];
  // --- B-staging mapping (g2l16 linear): 512 thr = 128 rows x 4 chunks ---
  const int srow = tid >> 2;                // 0..127
  const int scol = (tid & 3) * 8;
  const __bf16* Bb = Vt + (size_t)b * FVN * KN;
  // --- MFMA mapping: 8 waves = 2(q) x 4(fv); wave tile 32q x 128fv ---
  const int r = lane & 15, quad = lane >> 4;
  const int wq2 = (wave & 1) * 32;
  const int wf  = (wave >> 1) * 128;

  f32x4 acc[2][8] = {};
  bf16x8 s8; int4 am0, am1, al0, al1; float4 c0, c1, c2, c3;
  {
    const int kk = ac8 * 8;                 // prologue prefetch (t = 0)
    s8  = *(const bf16x8*)(Srow + kk);
    am0 = *(const int4*)(arow + kk); am1 = *(const int4*)(arow + kk + 4);
    al0 = *(const int4*)(lrow + kk); al1 = *(const int4*)(lrow + kk + 4);
    c0 = *(const float4*)(ckb + (size_t)kk * 2);
    c1 = *(const float4*)(ckb + (size_t)kk * 2 + 4);
    c2 = *(const float4*)(ckb + (size_t)kk * 2 + 8);
    c3 = *(const float4*)(ckb + (size_t)kk * 2 + 12);
  }
  for (int t = 0; t < KN / 64; ++t) {
    __syncthreads();                        // prev MFMA frag reads done
    {   // compute W chunk from prefetched regs, stage to As
      int   am[8] = {am0.x, am0.y, am0.z, am0.w, am1.x, am1.y, am1.z, am1.w};
      int   al[8] = {al0.x, al0.y, al0.z, al0.w, al1.x, al1.y, al1.z, al1.w};
      float kx[8] = {c0.x, c0.z, c1.x, c1.z, c2.x, c2.z, c3.x, c3.z};
      float ky[8] = {c0.y, c0.w, c1.y, c1.w, c2.y, c2.w, c3.y, c3.w};
      bf16x8 w8;
#pragma unroll
      for (int j = 0; j < 8; j++) {
        float p = __expf((float)s8[j]);
        float dx = qx - kx[j], dy = qy - ky[j];
        float sd = al[j] ? 0.f : sqrtf(dx * dx + dy * dy) * bs;
        float w = am[j] ? 0.f : (p * inv - sd);
        w8[j] = (__bf16)w;
      }
      *(bf16x8*)&As[ac8 >> 2][arow_i][(ac8 & 3) * 8] = w8;
    }
    const int k0 = t * 64;
#pragma unroll
    for (int h = 0; h < 2; h++)
#pragma unroll
      for (int rr = 0; rr < 4; rr++)
        g2l16(Bb + (size_t)(rr * 128 + srow) * KN + k0 + h * 32 + scol,
              &Bs[h][rr * 128 + wave * 16][0]);
    __syncthreads();                        // drain g2l + ds_writes
    if (t + 1 < KN / 64) {                  // issue-early: next A-chunk loads
      const int kk = (t + 1) * 64 + ac8 * 8;
      s8  = *(const bf16x8*)(Srow + kk);
      am0 = *(const int4*)(arow + kk); am1 = *(const int4*)(arow + kk + 4);
      al0 = *(const int4*)(lrow + kk); al1 = *(const int4*)(lrow + kk + 4);
      c0 = *(const float4*)(ckb + (size_t)kk * 2);
      c1 = *(const float4*)(ckb + (size_t)kk * 2 + 4);
      c2 = *(const float4*)(ckb + (size_t)kk * 2 + 8);
      c3 = *(const float4*)(ckb + (size_t)kk * 2 + 12);
    }
#pragma unroll
    for (int h = 0; h < 2; h++) {
      bf16x8 af[2], bv[8];
#pragma unroll
      for (int i = 0; i < 2; i++) af[i] = *(bf16x8*)&As[h][wq2 + i * 16 + r][quad * 8];
#pragma unroll
      for (int j = 0; j < 8; j++) bv[j] = *(bf16x8*)&Bs[h][wf + j * 16 + r][quad * 8];
#pragma unroll
      for (int i = 0; i < 2; i++)
#pragma unroll
        for (int j = 0; j < 8; j++)
          acc[i][j] = __builtin_amdgcn_mfma_f32_16x16x32_bf16(af[i], bv[j], acc[i][j], 0, 0, 0);
    }
  }
  // C/D layout: col(lane&15) = fv-frag row, row(quad*4+reg) = q
#pragma unroll
  for (int i = 0; i < 2; i++)
#pragma unroll
    for (int j = 0; j < 8; j++)
#pragma unroll
      for (int t4 = 0; t4 < 4; t4++) {
        int qq = q0 + qt + wq2 + i * 16 + quad * 4 + t4;
        int fv = wf + j * 16 + r;
        out[((size_t)b * QN + qq) * FVN + fv] = acc[i][j][t4];
      }
}

// ---------------------------------------------------------------------------
extern "C" void kernel_launch(void* const* d_in, const int* in_sizes, int n_in,
                              void* d_out, int out_size, void* d_ws, size_t ws_size,
                              hipStream_t stream) {
  (void)in_sizes; (void)n_in; (void)out_size;
  const float* qm   = (const float*)d_in[0];
  const float* km   = (const float*)d_in[1];
  const float* vm   = (const float*)d_in[2];
  const float* cq   = (const float*)d_in[3];
  const float* ck   = (const float*)d_in[4];
  const int*   attn = (const int*)d_in[5];
  const int*   alibi= (const int*)d_in[6];
  const float* bsp  = (const float*)d_in[7];
  float* out = (float*)d_out;

  // ws layout: [qb][kb][Vt][sums f32] fixed + [S: nb*qc*KN bf16]
  __bf16* qb  = (__bf16*)d_ws;
  __bf16* kb  = qb + (size_t)BN * QN * FN;
  __bf16* Vt  = kb + (size_t)BN * KN * FN;
  float*  sums = (float*)(Vt + (size_t)BN * FVN * KN);
  __bf16* Sws = (__bf16*)(sums + (size_t)BN * QN);
  const size_t fixed = ((size_t)BN * QN * FN + (size_t)BN * KN * FN +
                        (size_t)BN * FVN * KN) * 2 + (size_t)BN * QN * 4;
  int nb = BN, qc = QN;
  while (nb > 1 && fixed + (size_t)nb * qc * KN * 2 > ws_size) nb >>= 1;
  while (qc > 128 && fixed + (size_t)nb * qc * KN * 2 > ws_size) qc >>= 1;

  prep<<<dim3((BN * QN * FN) / 2048, 4), 256, 0, stream>>>(qm, km, vm, qb, kb, Vt, sums);
  for (int b0 = 0; b0 < BN; b0 += nb) {
    for (int q0 = 0; q0 < QN; q0 += qc) {
      gemm_s<<<dim3(qc / 128, KN / 128, nb), 256, 0, stream>>>(qb, kb, Sws, sums, b0, q0, qc);
      gemm_wv<<<dim3(nb * (qc / 64)), 512, 0, stream>>>(Sws, Vt, sums, cq, ck, attn,
                                                        alibi, bsp, out, b0, q0, qc, nb);
    }
  }
}

// Round 2
// 481.368 us; speedup vs baseline: 1.0380x; 1.0380x over previous
//
#include <hip/hip_runtime.h>
#include <hip/hip_bf16.h>
#include <math.h>

// Problem constants (from reference setup_inputs)
#define BN  8
#define QN  2048
#define KN  2048
#define FN  512
#define FVN 512

typedef __bf16 bf16x8 __attribute__((ext_vector_type(8)));
typedef __bf16 bf16x4v __attribute__((ext_vector_type(4)));
typedef float  f32x4  __attribute__((ext_vector_type(4)));

__device__ inline bf16x8 pack8(float4 a, float4 b) {
  bf16x8 r;
  r[0] = (__bf16)a.x; r[1] = (__bf16)a.y; r[2] = (__bf16)a.z; r[3] = (__bf16)a.w;
  r[4] = (__bf16)b.x; r[5] = (__bf16)b.y; r[6] = (__bf16)b.z; r[7] = (__bf16)b.w;
  return r;
}

// Async global->LDS, 16B/lane. LDS dest = wave-uniform base + lane*16 (m97).
__device__ __forceinline__ void g2l16(const __bf16* g, __bf16* l) {
  __builtin_amdgcn_global_load_lds(
      (const __attribute__((address_space(1))) void*)g,
      (__attribute__((address_space(3))) void*)l,
      16, 0, 0);
}

// ---------------------------------------------------------------------------
// Kernel 0 (prep): y==0 -> q convert (pre-scaled), y==1 -> k convert,
//                  y==2 -> v transpose to Vt[b, fv, k] bf16, y==3 -> zero sums.
// ---------------------------------------------------------------------------
__global__ __launch_bounds__(256) void prep(
    const float* __restrict__ qm, const float* __restrict__ km,
    const float* __restrict__ vm,
    __bf16* __restrict__ qb, __bf16* __restrict__ kb, __bf16* __restrict__ Vt,
    float* __restrict__ sums) {
  const int tid = threadIdx.x;
  if (blockIdx.y == 0) {
    const size_t idx = ((size_t)blockIdx.x * 256 + tid) * 8;
    const float scale = 0.044194173824159216f;  // 512^-0.5
    float4 a = *(const float4*)(qm + idx);
    float4 b = *(const float4*)(qm + idx + 4);
    a.x *= scale; a.y *= scale; a.z *= scale; a.w *= scale;
    b.x *= scale; b.y *= scale; b.z *= scale; b.w *= scale;
    *(bf16x8*)(qb + idx) = pack8(a, b);
  } else if (blockIdx.y == 1) {
    const size_t idx = ((size_t)blockIdx.x * 256 + tid) * 8;
    float4 a = *(const float4*)(km + idx);
    float4 b = *(const float4*)(km + idx + 4);
    *(bf16x8*)(kb + idx) = pack8(a, b);
  } else if (blockIdx.y == 2) {
    // v transpose: 2048 logical blocks; bx = ((b*8)+fblk)*32 + kblk
    const int bx = blockIdx.x;
    if (bx >= (KN / 64) * (FVN / 64) * BN) return;
    const int b  = bx >> 8;                 // /(32*8)
    const int f0 = ((bx >> 5) & 7) * 64;
    const int k0 = (bx & 31) * 64;
    __shared__ float tile[64][65];
    const int r = tid >> 4;          // 0..15
    const int c = (tid & 15) * 4;    // 0..60
#pragma unroll
    for (int i = 0; i < 4; i++) {
      float4 u = *(const float4*)(vm + ((size_t)b * KN + k0 + r + i * 16) * FVN + f0 + c);
      tile[r + i * 16][c] = u.x; tile[r + i * 16][c + 1] = u.y;
      tile[r + i * 16][c + 2] = u.z; tile[r + i * 16][c + 3] = u.w;
    }
    __syncthreads();
#pragma unroll
    for (int i = 0; i < 4; i++) {
      int fv = r + i * 16;
      bf16x4v w;
      w[0] = (__bf16)tile[c][fv];     w[1] = (__bf16)tile[c + 1][fv];
      w[2] = (__bf16)tile[c + 2][fv]; w[3] = (__bf16)tile[c + 3][fv];
      *(bf16x4v*)(Vt + ((size_t)b * FVN + f0 + fv) * KN + k0 + c) = w;
    }
  } else {
    // zero sums[BN*QN] f32 = 64 KB: 16 blocks x 256 thr x 16B
    if (blockIdx.x < (BN * QN) / 1024) {
      float4 z4; z4.x = 0.f; z4.y = 0.f; z4.z = 0.f; z4.w = 0.f;
      ((float4*)sums)[(size_t)blockIdx.x * 256 + tid] = z4;
    }
  }
}

// ---------------------------------------------------------------------------
// Kernel 1: S[z,q,k] = (bf16) dot(qb[b,q,:], kb[b,k,:])   (scale pre-folded)
// 128x128 tile, BK=64 as two m97-verified [128][32] LDS half-tiles.
// Epilogue accumulates row-sums of exp(S) (f32 accs) into sums[b,q]
// (16-lane shfl reduce -> 1 atomicAdd per row per wave).  [round-1 verified]
// ---------------------------------------------------------------------------
__global__ __launch_bounds__(256) void gemm_s(
    const __bf16* __restrict__ qb, const __bf16* __restrict__ kb,
    __bf16* __restrict__ Sws, float* __restrict__ sums,
    int b0, int q0, int qchunk) {
  __shared__ __align__(16) __bf16 As[2][128][32];  // 16 KB, k-half h
  __shared__ __align__(16) __bf16 Bs[2][128][32];
  const int tid = threadIdx.x;
  const int lane = tid & 63, wave = tid >> 6;
  const int wq = (wave & 1) * 64, wk = (wave >> 1) * 64;
  const int qt = blockIdx.x * 128, kt = blockIdx.y * 128;
  const int z = blockIdx.z, b = b0 + z;
  __bf16* S = Sws + (size_t)z * qchunk * KN;
  const __bf16* Ab = qb + ((size_t)b * QN + q0 + qt) * FN;
  const __bf16* Bb = kb + ((size_t)b * KN + kt) * FN;
  const int srow = lane >> 2;         // 0..15 within 16-row group
  const int scol = (lane & 3) * 8;    // bf16 col within 32
  const int r = lane & 15, quad = lane >> 4;
  f32x4 acc[4][4] = {};
  for (int f0 = 0; f0 < FN; f0 += 64) {
    __syncthreads();                  // prev-iter frag reads done
#pragma unroll
    for (int h = 0; h < 2; h++) {
      const int co = f0 + h * 32 + scol;
      g2l16(Ab + (size_t)(wave * 32 + srow) * FN + co,      &As[h][wave * 32][0]);
      g2l16(Ab + (size_t)(wave * 32 + 16 + srow) * FN + co, &As[h][wave * 32 + 16][0]);
      g2l16(Bb + (size_t)(wave * 32 + srow) * FN + co,      &Bs[h][wave * 32][0]);
      g2l16(Bb + (size_t)(wave * 32 + 16 + srow) * FN + co, &Bs[h][wave * 32 + 16][0]);
    }
    __syncthreads();                  // vmcnt drain + visibility
#pragma unroll
    for (int h = 0; h < 2; h++) {
      bf16x8 af[4], bf[4];
#pragma unroll
      for (int i = 0; i < 4; i++) af[i] = *(bf16x8*)&As[h][wq + i * 16 + r][quad * 8];
#pragma unroll
      for (int j = 0; j < 4; j++) bf[j] = *(bf16x8*)&Bs[h][wk + j * 16 + r][quad * 8];
#pragma unroll
      for (int i = 0; i < 4; i++)
#pragma unroll
        for (int j = 0; j < 4; j++)
          acc[i][j] = __builtin_amdgcn_mfma_f32_16x16x32_bf16(af[i], bf[j], acc[i][j], 0, 0, 0);
    }
  }
  // C/D layout (m89-verified): col = lane&15 (=k), row = quad*4+reg (=q)
#pragma unroll
  for (int i = 0; i < 4; i++)
#pragma unroll
    for (int j = 0; j < 4; j++)
#pragma unroll
      for (int t = 0; t < 4; t++) {
        int qq = qt + wq + i * 16 + quad * 4 + t;
        int kk = kt + wk + j * 16 + r;
        S[(size_t)qq * KN + kk] = (__bf16)acc[i][j][t];
      }
  // Row-sum of exp over this block's 64 k-cols per wave (denominator is
  // UNMASKED sum over all k; partials from the 16 kt-blocks accumulate).
#pragma unroll
  for (int i = 0; i < 4; i++)
#pragma unroll
    for (int t = 0; t < 4; t++) {
      float part = 0.f;
#pragma unroll
      for (int j = 0; j < 4; j++) part += __expf(acc[i][j][t]);
      part += __shfl_xor(part, 1);
      part += __shfl_xor(part, 2);
      part += __shfl_xor(part, 4);
      part += __shfl_xor(part, 8);
      if (r == 0)
        atomicAdd(&sums[(size_t)b * QN + q0 + qt + wq + i * 16 + quad * 4 + t], part);
    }
}

// ---------------------------------------------------------------------------
// Kernel 2: in-place W = attn ? 0 : (exp(S)*inv - (alibi ? 0 : dist*bs))
// Pure streaming (no reduce; inv comes from gemm_s's sums epilogue).
// All global loads issued up-front for MLP; k-coords staged in LDS per block.
// Wave-per-row, 4 waves/block; lane owns 4 chunks of 8 contiguous k.
// ---------------------------------------------------------------------------
__global__ __launch_bounds__(256) void softmax_w(
    __bf16* __restrict__ Sws,
    const float* __restrict__ cq, const float* __restrict__ ck,
    const int* __restrict__ attn, const int* __restrict__ alibi,
    const float* __restrict__ bsp, const float* __restrict__ sums,
    int b0, int q0, int qchunk) {
  __shared__ float ckx[KN], cky[KN];   // 16 KB
  const int z = blockIdx.z, b = b0 + z;
  const int lane = threadIdx.x & 63, wave = threadIdx.x >> 6;
  const int ql = blockIdx.x * 4 + wave;   // local q row in chunk
  const int qg = q0 + ql;                 // global q
  __bf16* Srow = Sws + ((size_t)z * qchunk + ql) * KN;
  const int* arow = attn + ((size_t)b * QN + qg) * KN;
  const int* lrow = alibi + ((size_t)b * QN + qg) * KN;
  const float* ckb = ck + (size_t)b * KN * 2;
  // --- issue ALL global loads up front (S row + both masks + scalars) ---
  bf16x8 s8[4]; int4 am[8], al[8];
#pragma unroll
  for (int c = 0; c < 4; c++) {
    const int k0 = c * 512 + lane * 8;
    s8[c]       = *(const bf16x8*)(Srow + k0);
    am[c * 2]     = *(const int4*)(arow + k0);
    am[c * 2 + 1] = *(const int4*)(arow + k0 + 4);
    al[c * 2]     = *(const int4*)(lrow + k0);
    al[c * 2 + 1] = *(const int4*)(lrow + k0 + 4);
  }
  const float inv = 1.0f / sums[(size_t)b * QN + qg];
  const float qx = cq[((size_t)b * QN + qg) * 2 + 0];
  const float qy = cq[((size_t)b * QN + qg) * 2 + 1];
  const float bs = bsp[0];
  // --- stage this batch's k coords to LDS (hides the global latency) ---
  for (int i = threadIdx.x; i < KN / 2; i += 256) {
    float4 u = *(const float4*)(ckb + (size_t)i * 4);
    ckx[2 * i] = u.x;     cky[2 * i] = u.y;
    ckx[2 * i + 1] = u.z; cky[2 * i + 1] = u.w;
  }
  __syncthreads();
  // --- streaming output phase, no cross-lane deps ---
#pragma unroll
  for (int c = 0; c < 4; c++) {
    const int k0 = c * 512 + lane * 8;
    float4 x0 = *(const float4*)&ckx[k0]; float4 x1 = *(const float4*)&ckx[k0 + 4];
    float4 y0 = *(const float4*)&cky[k0]; float4 y1 = *(const float4*)&cky[k0 + 4];
    float kx[8] = {x0.x, x0.y, x0.z, x0.w, x1.x, x1.y, x1.z, x1.w};
    float ky[8] = {y0.x, y0.y, y0.z, y0.w, y1.x, y1.y, y1.z, y1.w};
    int amv[8] = {am[c * 2].x, am[c * 2].y, am[c * 2].z, am[c * 2].w,
                  am[c * 2 + 1].x, am[c * 2 + 1].y, am[c * 2 + 1].z, am[c * 2 + 1].w};
    int alv[8] = {al[c * 2].x, al[c * 2].y, al[c * 2].z, al[c * 2].w,
                  al[c * 2 + 1].x, al[c * 2 + 1].y, al[c * 2 + 1].z, al[c * 2 + 1].w};
    bf16x8 w8;
#pragma unroll
    for (int j = 0; j < 8; j++) {
      float p = __expf((float)s8[c][j]) * inv;
      float dx = qx - kx[j], dy = qy - ky[j];
      float sd = alv[j] ? 0.f : sqrtf(dx * dx + dy * dy) * bs;
      w8[j] = (__bf16)(amv[j] ? 0.f : (p - sd));
    }
    *(bf16x8*)(Srow + k0) = w8;
  }
}

// ---------------------------------------------------------------------------
// Kernel 3: out[b,q,fv] = sum_k W[q,k] * Vt[fv,k] — bf16 GEMM, BK=64.
// ---------------------------------------------------------------------------
__global__ __launch_bounds__(256) void gemm_w(
    const __bf16* __restrict__ W, const __bf16* __restrict__ Vt,
    float* __restrict__ out, int b0, int q0, int qchunk) {
  __shared__ __align__(16) __bf16 As[2][128][32];  // [q][k]
  __shared__ __align__(16) __bf16 Bs[2][128][32];  // [fv][k]
  const int tid = threadIdx.x;
  const int lane = tid & 63, wave = tid >> 6;
  const int wq = (wave & 1) * 64, wf = (wave >> 1) * 64;
  const int qt = blockIdx.x * 128, ft = blockIdx.y * 128;
  const int z = blockIdx.z, b = b0 + z;
  const __bf16* Ab = W + ((size_t)z * qchunk + qt) * KN;
  const __bf16* Bb = Vt + ((size_t)b * FVN + ft) * KN;
  const int srow = lane >> 2;
  const int scol = (lane & 3) * 8;
  const int r = lane & 15, quad = lane >> 4;
  f32x4 acc[4][4] = {};
  for (int k0 = 0; k0 < KN; k0 += 64) {
    __syncthreads();
#pragma unroll
    for (int h = 0; h < 2; h++) {
      const int co = k0 + h * 32 + scol;
      g2l16(Ab + (size_t)(wave * 32 + srow) * KN + co,      &As[h][wave * 32][0]);
      g2l16(Ab + (size_t)(wave * 32 + 16 + srow) * KN + co, &As[h][wave * 32 + 16][0]);
      g2l16(Bb + (size_t)(wave * 32 + srow) * KN + co,      &Bs[h][wave * 32][0]);
      g2l16(Bb + (size_t)(wave * 32 + 16 + srow) * KN + co, &Bs[h][wave * 32 + 16][0]);
    }
    __syncthreads();
#pragma unroll
    for (int h = 0; h < 2; h++) {
      bf16x8 af[4], bf[4];
#pragma unroll
      for (int i = 0; i < 4; i++) af[i] = *(bf16x8*)&As[h][wq + i * 16 + r][quad * 8];
#pragma unroll
      for (int j = 0; j < 4; j++) bf[j] = *(bf16x8*)&Bs[h][wf + j * 16 + r][quad * 8];
#pragma unroll
      for (int i = 0; i < 4; i++)
#pragma unroll
        for (int j = 0; j < 4; j++)
          acc[i][j] = __builtin_amdgcn_mfma_f32_16x16x32_bf16(af[i], bf[j], acc[i][j], 0, 0, 0);
    }
  }
#pragma unroll
  for (int i = 0; i < 4; i++)
#pragma unroll
    for (int j = 0; j < 4; j++)
#pragma unroll
      for (int t = 0; t < 4; t++) {
        int qq = q0 + qt + wq + i * 16 + quad * 4 + t;
        int fv = ft + wf + j * 16 + r;
        out[((size_t)b * QN + qq) * FVN + fv] = acc[i][j][t];
      }
}

// ---------------------------------------------------------------------------
extern "C" void kernel_launch(void* const* d_in, const int* in_sizes, int n_in,
                              void* d_out, int out_size, void* d_ws, size_t ws_size,
                              hipStream_t stream) {
  (void)in_sizes; (void)n_in; (void)out_size;
  const float* qm   = (const float*)d_in[0];
  const float* km   = (const float*)d_in[1];
  const float* vm   = (const float*)d_in[2];
  const float* cq   = (const float*)d_in[3];
  const float* ck   = (const float*)d_in[4];
  const int*   attn = (const int*)d_in[5];
  const int*   alibi= (const int*)d_in[6];
  const float* bsp  = (const float*)d_in[7];
  float* out = (float*)d_out;

  // ws layout: [qb][kb][Vt][sums f32] fixed + [S/W: nb*qc*KN bf16]
  __bf16* qb  = (__bf16*)d_ws;
  __bf16* kb  = qb + (size_t)BN * QN * FN;
  __bf16* Vt  = kb + (size_t)BN * KN * FN;
  float*  sums = (float*)(Vt + (size_t)BN * FVN * KN);
  __bf16* Sws = (__bf16*)(sums + (size_t)BN * QN);
  const size_t fixed = ((size_t)BN * QN * FN + (size_t)BN * KN * FN +
                        (size_t)BN * FVN * KN) * 2 + (size_t)BN * QN * 4;
  int nb = BN, qc = QN;
  while (nb > 1 && fixed + (size_t)nb * qc * KN * 2 > ws_size) nb >>= 1;
  while (qc > 128 && fixed + (size_t)nb * qc * KN * 2 > ws_size) qc >>= 1;

  prep<<<dim3((BN * QN * FN) / 2048, 4), 256, 0, stream>>>(qm, km, vm, qb, kb, Vt, sums);
  for (int b0 = 0; b0 < BN; b0 += nb) {
    for (int q0 = 0; q0 < QN; q0 += qc) {
      gemm_s<<<dim3(qc / 128, KN / 128, nb), 256, 0, stream>>>(qb, kb, Sws, sums, b0, q0, qc);
      softmax_w<<<dim3(qc / 4, 1, nb), 256, 0, stream>>>(Sws, cq, ck, attn, alibi, bsp,
                                                         sums, b0, q0, qc);
      gemm_w<<<dim3(qc / 128, FVN / 128, nb), 256, 0, stream>>>(Sws, Vt, out, b0, q0, qc);
    }
  }
}

// Round 3
// 473.235 us; speedup vs baseline: 1.0558x; 1.0172x over previous
//
#include <hip/hip_runtime.h>
#include <hip/hip_bf16.h>
#include <math.h>

// Problem constants (from reference setup_inputs)
#define BN  8
#define QN  2048
#define KN  2048
#define FN  512
#define FVN 512

typedef __bf16 bf16x8 __attribute__((ext_vector_type(8)));
typedef __bf16 bf16x4v __attribute__((ext_vector_type(4)));
typedef float  f32x4  __attribute__((ext_vector_type(4)));

__device__ inline bf16x8 pack8(float4 a, float4 b) {
  bf16x8 r;
  r[0] = (__bf16)a.x; r[1] = (__bf16)a.y; r[2] = (__bf16)a.z; r[3] = (__bf16)a.w;
  r[4] = (__bf16)b.x; r[5] = (__bf16)b.y; r[6] = (__bf16)b.z; r[7] = (__bf16)b.w;
  return r;
}

// Async global->LDS, 16B/lane. LDS dest = wave-uniform base + lane*16 (m97).
__device__ __forceinline__ void g2l16(const __bf16* g, __bf16* l) {
  __builtin_amdgcn_global_load_lds(
      (const __attribute__((address_space(1))) void*)g,
      (__attribute__((address_space(3))) void*)l,
      16, 0, 0);
}
__device__ __forceinline__ void g2l16v(const void* g, void* l) {
  __builtin_amdgcn_global_load_lds(
      (const __attribute__((address_space(1))) void*)g,
      (__attribute__((address_space(3))) void*)l,
      16, 0, 0);
}

// ---------------------------------------------------------------------------
// Kernel 0 (prep): y==0 -> q convert (pre-scaled), y==1 -> k convert,
//                  y==2 -> v transpose to Vt[b, fv, k] bf16, y==3 -> zero sums.
// ---------------------------------------------------------------------------
__global__ __launch_bounds__(256) void prep(
    const float* __restrict__ qm, const float* __restrict__ km,
    const float* __restrict__ vm,
    __bf16* __restrict__ qb, __bf16* __restrict__ kb, __bf16* __restrict__ Vt,
    float* __restrict__ sums) {
  const int tid = threadIdx.x;
  if (blockIdx.y == 0) {
    const size_t idx = ((size_t)blockIdx.x * 256 + tid) * 8;
    const float scale = 0.044194173824159216f;  // 512^-0.5
    float4 a = *(const float4*)(qm + idx);
    float4 b = *(const float4*)(qm + idx + 4);
    a.x *= scale; a.y *= scale; a.z *= scale; a.w *= scale;
    b.x *= scale; b.y *= scale; b.z *= scale; b.w *= scale;
    *(bf16x8*)(qb + idx) = pack8(a, b);
  } else if (blockIdx.y == 1) {
    const size_t idx = ((size_t)blockIdx.x * 256 + tid) * 8;
    float4 a = *(const float4*)(km + idx);
    float4 b = *(const float4*)(km + idx + 4);
    *(bf16x8*)(kb + idx) = pack8(a, b);
  } else if (blockIdx.y == 2) {
    // v transpose: 2048 logical blocks; bx = ((b*8)+fblk)*32 + kblk
    const int bx = blockIdx.x;
    if (bx >= (KN / 64) * (FVN / 64) * BN) return;
    const int b  = bx >> 8;                 // /(32*8)
    const int f0 = ((bx >> 5) & 7) * 64;
    const int k0 = (bx & 31) * 64;
    __shared__ float tile[64][65];
    const int r = tid >> 4;          // 0..15
    const int c = (tid & 15) * 4;    // 0..60
#pragma unroll
    for (int i = 0; i < 4; i++) {
      float4 u = *(const float4*)(vm + ((size_t)b * KN + k0 + r + i * 16) * FVN + f0 + c);
      tile[r + i * 16][c] = u.x; tile[r + i * 16][c + 1] = u.y;
      tile[r + i * 16][c + 2] = u.z; tile[r + i * 16][c + 3] = u.w;
    }
    __syncthreads();
#pragma unroll
    for (int i = 0; i < 4; i++) {
      int fv = r + i * 16;
      bf16x4v w;
      w[0] = (__bf16)tile[c][fv];     w[1] = (__bf16)tile[c + 1][fv];
      w[2] = (__bf16)tile[c + 2][fv]; w[3] = (__bf16)tile[c + 3][fv];
      *(bf16x4v*)(Vt + ((size_t)b * FVN + f0 + fv) * KN + k0 + c) = w;
    }
  } else {
    // zero sums[BN*QN] f32 = 64 KB: 16 blocks x 256 thr x 16B
    if (blockIdx.x < (BN * QN) / 1024) {
      float4 z4; z4.x = 0.f; z4.y = 0.f; z4.z = 0.f; z4.w = 0.f;
      ((float4*)sums)[(size_t)blockIdx.x * 256 + tid] = z4;
    }
  }
}

// ---------------------------------------------------------------------------
// Kernel 1: S[z,q,k] = (bf16) dot(qb[b,q,:], kb[b,k,:])   (scale pre-folded)
// 128x128 tile, BK=64 as two m97-verified [128][32] LDS half-tiles.
// Epilogue accumulates row-sums of exp(S) (f32 accs) into sums[b,q]
// (16-lane shfl reduce -> 1 atomicAdd per row per wave).  [round-1 verified]
// ---------------------------------------------------------------------------
__global__ __launch_bounds__(256) void gemm_s(
    const __bf16* __restrict__ qb, const __bf16* __restrict__ kb,
    __bf16* __restrict__ Sws, float* __restrict__ sums,
    int b0, int q0, int qchunk) {
  __shared__ __align__(16) __bf16 As[2][128][32];  // 16 KB, k-half h
  __shared__ __align__(16) __bf16 Bs[2][128][32];
  const int tid = threadIdx.x;
  const int lane = tid & 63, wave = tid >> 6;
  const int wq = (wave & 1) * 64, wk = (wave >> 1) * 64;
  const int qt = blockIdx.x * 128, kt = blockIdx.y * 128;
  const int z = blockIdx.z, b = b0 + z;
  __bf16* S = Sws + (size_t)z * qchunk * KN;
  const __bf16* Ab = qb + ((size_t)b * QN + q0 + qt) * FN;
  const __bf16* Bb = kb + ((size_t)b * KN + kt) * FN;
  const int srow = lane >> 2;         // 0..15 within 16-row group
  const int scol = (lane & 3) * 8;    // bf16 col within 32
  const int r = lane & 15, quad = lane >> 4;
  f32x4 acc[4][4] = {};
  for (int f0 = 0; f0 < FN; f0 += 64) {
    __syncthreads();                  // prev-iter frag reads done
#pragma unroll
    for (int h = 0; h < 2; h++) {
      const int co = f0 + h * 32 + scol;
      g2l16(Ab + (size_t)(wave * 32 + srow) * FN + co,      &As[h][wave * 32][0]);
      g2l16(Ab + (size_t)(wave * 32 + 16 + srow) * FN + co, &As[h][wave * 32 + 16][0]);
      g2l16(Bb + (size_t)(wave * 32 + srow) * FN + co,      &Bs[h][wave * 32][0]);
      g2l16(Bb + (size_t)(wave * 32 + 16 + srow) * FN + co, &Bs[h][wave * 32 + 16][0]);
    }
    __syncthreads();                  // vmcnt drain + visibility
#pragma unroll
    for (int h = 0; h < 2; h++) {
      bf16x8 af[4], bf[4];
#pragma unroll
      for (int i = 0; i < 4; i++) af[i] = *(bf16x8*)&As[h][wq + i * 16 + r][quad * 8];
#pragma unroll
      for (int j = 0; j < 4; j++) bf[j] = *(bf16x8*)&Bs[h][wk + j * 16 + r][quad * 8];
#pragma unroll
      for (int i = 0; i < 4; i++)
#pragma unroll
        for (int j = 0; j < 4; j++)
          acc[i][j] = __builtin_amdgcn_mfma_f32_16x16x32_bf16(af[i], bf[j], acc[i][j], 0, 0, 0);
    }
  }
  // C/D layout (m89-verified): col = lane&15 (=k), row = quad*4+reg (=q)
#pragma unroll
  for (int i = 0; i < 4; i++)
#pragma unroll
    for (int j = 0; j < 4; j++)
#pragma unroll
      for (int t = 0; t < 4; t++) {
        int qq = qt + wq + i * 16 + quad * 4 + t;
        int kk = kt + wk + j * 16 + r;
        S[(size_t)qq * KN + kk] = (__bf16)acc[i][j][t];
      }
  // Row-sum of exp over this block's 64 k-cols per wave (denominator is
  // UNMASKED sum over all k; partials from the 16 kt-blocks accumulate).
#pragma unroll
  for (int i = 0; i < 4; i++)
#pragma unroll
    for (int t = 0; t < 4; t++) {
      float part = 0.f;
#pragma unroll
      for (int j = 0; j < 4; j++) part += __expf(acc[i][j][t]);
      part += __shfl_xor(part, 1);
      part += __shfl_xor(part, 2);
      part += __shfl_xor(part, 4);
      part += __shfl_xor(part, 8);
      if (r == 0)
        atomicAdd(&sums[(size_t)b * QN + q0 + qt + wq + i * 16 + quad * 4 + t], part);
    }
}

// ---------------------------------------------------------------------------
// Kernel 2: in-place W = attn ? 0 : (exp(S)*inv - (alibi ? 0 : dist*bs))
// One q-row per block (256 thr). S + both masks staged via global_load_lds
// (no VGPR landing space -> deep vmcnt queue; 5 g2l16/wave x 1KB in flight).
// LDS 20KB -> 8 blocks/CU. Consumption in 4-elem groups: all LDS reads are
// lane-stride 8B/16B (conflict-free). Coords read from global (L2-hot).
// inv comes from gemm_s's f32-acc sums epilogue (round-1 verified numerics).
// ---------------------------------------------------------------------------
__global__ __launch_bounds__(256) void softmax_w(
    __bf16* __restrict__ Sws,
    const float* __restrict__ cq, const float* __restrict__ ck,
    const int* __restrict__ attn, const int* __restrict__ alibi,
    const float* __restrict__ bsp, const float* __restrict__ sums,
    int b0, int q0, int qchunk) {
  __shared__ __align__(16) __bf16 S_lds[KN];   // 4 KB
  __shared__ __align__(16) int    am_lds[KN];  // 8 KB
  __shared__ __align__(16) int    al_lds[KN];  // 8 KB
  const int tid = threadIdx.x;
  const int lane = tid & 63, wave = tid >> 6;
  const int z = blockIdx.z, b = b0 + z;
  const int ql = blockIdx.x;              // local q row in chunk
  const int qg = q0 + ql;                 // global q
  __bf16* Srow = Sws + ((size_t)z * qchunk + ql) * KN;
  const int* arow = attn + ((size_t)b * QN + qg) * KN;
  const int* lrow = alibi + ((size_t)b * QN + qg) * KN;
  const float* ckb = ck + (size_t)b * KN * 2;
  // --- stage S (4x1KB) + attn (8x1KB) + alibi (8x1KB) via g2l16 ---
  // wave w: S seg w; attn segs w, w+4; alibi segs w, w+4  => 5 g2l/wave
  g2l16v((const char*)Srow + wave * 1024 + lane * 16,
         (char*)S_lds + wave * 1024);
#pragma unroll
  for (int s = 0; s < 2; s++) {
    const int seg = wave + s * 4;
    g2l16v((const char*)arow + seg * 1024 + lane * 16, (char*)am_lds + seg * 1024);
    g2l16v((const char*)lrow + seg * 1024 + lane * 16, (char*)al_lds + seg * 1024);
  }
  // --- per-thread coord loads (global, L2-hot) + uniform scalars ---
  const int k0g = tid * 4;            // group 0 k-base
  const int k1g = 1024 + tid * 4;     // group 1 k-base
  float4 c00 = *(const float4*)(ckb + (size_t)k0g * 2);
  float4 c01 = *(const float4*)(ckb + (size_t)k0g * 2 + 4);
  float4 c10 = *(const float4*)(ckb + (size_t)k1g * 2);
  float4 c11 = *(const float4*)(ckb + (size_t)k1g * 2 + 4);
  const float inv = 1.0f / sums[(size_t)b * QN + qg];
  const float qx = cq[((size_t)b * QN + qg) * 2 + 0];
  const float qy = cq[((size_t)b * QN + qg) * 2 + 1];
  const float bs = bsp[0];
  __syncthreads();   // drains vmcnt(0) + lgkmcnt(0), then barrier
  // --- consume: 2 groups of 4 contiguous k per thread ---
#pragma unroll
  for (int g = 0; g < 2; g++) {
    const int k = g ? k1g : k0g;
    bf16x4v s4 = *(const bf16x4v*)((const char*)S_lds + (size_t)k * 2);
    int4 am4 = *(const int4*)&am_lds[k];
    int4 al4 = *(const int4*)&al_lds[k];
    float4 ca = g ? c10 : c00;
    float4 cb = g ? c11 : c01;
    float kx[4] = {ca.x, ca.z, cb.x, cb.z};
    float ky[4] = {ca.y, ca.w, cb.y, cb.w};
    int amv[4] = {am4.x, am4.y, am4.z, am4.w};
    int alv[4] = {al4.x, al4.y, al4.z, al4.w};
    bf16x4v w4;
#pragma unroll
    for (int j = 0; j < 4; j++) {
      float p = __expf((float)s4[j]) * inv;
      float dx = qx - kx[j], dy = qy - ky[j];
      float sd = alv[j] ? 0.f : sqrtf(dx * dx + dy * dy) * bs;
      w4[j] = (__bf16)(amv[j] ? 0.f : (p - sd));
    }
    *(bf16x4v*)(Srow + k) = w4;
  }
}

// ---------------------------------------------------------------------------
// Kernel 3: out[b,q,fv] = sum_k W[q,k] * Vt[fv,k] — bf16 GEMM, BK=64.
// ---------------------------------------------------------------------------
__global__ __launch_bounds__(256) void gemm_w(
    const __bf16* __restrict__ W, const __bf16* __restrict__ Vt,
    float* __restrict__ out, int b0, int q0, int qchunk) {
  __shared__ __align__(16) __bf16 As[2][128][32];  // [q][k]
  __shared__ __align__(16) __bf16 Bs[2][128][32];  // [fv][k]
  const int tid = threadIdx.x;
  const int lane = tid & 63, wave = tid >> 6;
  const int wq = (wave & 1) * 64, wf = (wave >> 1) * 64;
  const int qt = blockIdx.x * 128, ft = blockIdx.y * 128;
  const int z = blockIdx.z, b = b0 + z;
  const __bf16* Ab = W + ((size_t)z * qchunk + qt) * KN;
  const __bf16* Bb = Vt + ((size_t)b * FVN + ft) * KN;
  const int srow = lane >> 2;
  const int scol = (lane & 3) * 8;
  const int r = lane & 15, quad = lane >> 4;
  f32x4 acc[4][4] = {};
  for (int k0 = 0; k0 < KN; k0 += 64) {
    __syncthreads();
#pragma unroll
    for (int h = 0; h < 2; h++) {
      const int co = k0 + h * 32 + scol;
      g2l16(Ab + (size_t)(wave * 32 + srow) * KN + co,      &As[h][wave * 32][0]);
      g2l16(Ab + (size_t)(wave * 32 + 16 + srow) * KN + co, &As[h][wave * 32 + 16][0]);
      g2l16(Bb + (size_t)(wave * 32 + srow) * KN + co,      &Bs[h][wave * 32][0]);
      g2l16(Bb + (size_t)(wave * 32 + 16 + srow) * KN + co, &Bs[h][wave * 32 + 16][0]);
    }
    __syncthreads();
#pragma unroll
    for (int h = 0; h < 2; h++) {
      bf16x8 af[4], bf[4];
#pragma unroll
      for (int i = 0; i < 4; i++) af[i] = *(bf16x8*)&As[h][wq + i * 16 + r][quad * 8];
#pragma unroll
      for (int j = 0; j < 4; j++) bf[j] = *(bf16x8*)&Bs[h][wf + j * 16 + r][quad * 8];
#pragma unroll
      for (int i = 0; i < 4; i++)
#pragma unroll
        for (int j = 0; j < 4; j++)
          acc[i][j] = __builtin_amdgcn_mfma_f32_16x16x32_bf16(af[i], bf[j], acc[i][j], 0, 0, 0);
    }
  }
#pragma unroll
  for (int i = 0; i < 4; i++)
#pragma unroll
    for (int j = 0; j < 4; j++)
#pragma unroll
      for (int t = 0; t < 4; t++) {
        int qq = q0 + qt + wq + i * 16 + quad * 4 + t;
        int fv = ft + wf + j * 16 + r;
        out[((size_t)b * QN + qq) * FVN + fv] = acc[i][j][t];
      }
}

// ---------------------------------------------------------------------------
extern "C" void kernel_launch(void* const* d_in, const int* in_sizes, int n_in,
                              void* d_out, int out_size, void* d_ws, size_t ws_size,
                              hipStream_t stream) {
  (void)in_sizes; (void)n_in; (void)out_size;
  const float* qm   = (const float*)d_in[0];
  const float* km   = (const float*)d_in[1];
  const float* vm   = (const float*)d_in[2];
  const float* cq   = (const float*)d_in[3];
  const float* ck   = (const float*)d_in[4];
  const int*   attn = (const int*)d_in[5];
  const int*   alibi= (const int*)d_in[6];
  const float* bsp  = (const float*)d_in[7];
  float* out = (float*)d_out;

  // ws layout: [qb][kb][Vt][sums f32] fixed + [S/W: nb*qc*KN bf16]
  __bf16* qb  = (__bf16*)d_ws;
  __bf16* kb  = qb + (size_t)BN * QN * FN;
  __bf16* Vt  = kb + (size_t)BN * KN * FN;
  float*  sums = (float*)(Vt + (size_t)BN * FVN * KN);
  __bf16* Sws = (__bf16*)(sums + (size_t)BN * QN);
  const size_t fixed = ((size_t)BN * QN * FN + (size_t)BN * KN * FN +
                        (size_t)BN * FVN * KN) * 2 + (size_t)BN * QN * 4;
  int nb = BN, qc = QN;
  while (nb > 1 && fixed + (size_t)nb * qc * KN * 2 > ws_size) nb >>= 1;
  while (qc > 128 && fixed + (size_t)nb * qc * KN * 2 > ws_size) qc >>= 1;

  prep<<<dim3((BN * QN * FN) / 2048, 4), 256, 0, stream>>>(qm, km, vm, qb, kb, Vt, sums);
  for (int b0 = 0; b0 < BN; b0 += nb) {
    for (int q0 = 0; q0 < QN; q0 += qc) {
      gemm_s<<<dim3(qc / 128, KN / 128, nb), 256, 0, stream>>>(qb, kb, Sws, sums, b0, q0, qc);
      softmax_w<<<dim3(qc, 1, nb), 256, 0, stream>>>(Sws, cq, ck, attn, alibi, bsp,
                                                     sums, b0, q0, qc);
      gemm_w<<<dim3(qc / 128, FVN / 128, nb), 256, 0, stream>>>(Sws, Vt, out, b0, q0, qc);
    }
  }
}